// Round 6
// baseline (132.202 us; speedup 1.0000x reference)
//
#include <hip/hip_runtime.h>
#include <stdint.h>

#define NSK 1000
#define TT  200
#define BB  64
#define NROW (BB * TT)      // 12800
#define NOUT (BB * (TT-1))  // 12736
#define SCH 10              // scan chunk (steps); red dbuf = 2*SCH*256 floats = 20 KB
#define RW  2               // scan Mv rows per wave (8-way M split)
#define NSPLIT 8
#define PSTR ((size_t)NROW * 64)   // partial-array stride (elements)

__device__ __forceinline__ unsigned ulane_bcast(unsigned v, int l) {
  return __builtin_amdgcn_readlane(v, l);
}
__device__ __forceinline__ float frcp(float x) { return __builtin_amdgcn_rcpf(x); }
__device__ __forceinline__ float sigm(float x) { return frcp(1.f + __expf(-x)); }
__device__ __forceinline__ float tanh_fast(float x) {
  return fmaf(-2.f, frcp(1.f + __expf(2.f * x)), 1.f);   // 1 - 2/(1+e^2x)
}

typedef _Float16 half2v __attribute__((ext_vector_type(2)));
typedef _Float16 v8h __attribute__((ext_vector_type(8)));   // MFMA A/B frag (4 VGPR)
typedef float    v4f __attribute__((ext_vector_type(4)));   // MFMA C/D frag
union H2U { unsigned u; half2v h; };
union V8U { uint4 u; v8h h; };
__device__ __forceinline__ unsigned pack2h(float a, float b) {
  H2U x; x.h = (half2v){(_Float16)a, (_Float16)b}; return x.u;
}
__device__ __forceinline__ unsigned short f16bits(float x) {
  H2U u; u.h = (half2v){(_Float16)x, (_Float16)0.f}; return (unsigned short)(u.u & 0xffffu);
}
__device__ __forceinline__ float f16lo(unsigned bits) {
  H2U u; u.u = bits; return (float)u.h.x;
}
__device__ __forceinline__ float f16hi(unsigned bits) {
  H2U u; u.u = bits; return (float)u.h.y;
}
__device__ __forceinline__ v8h pk8(float4 x0, float4 x1) {
  return (v8h){(_Float16)x0.x, (_Float16)x0.y, (_Float16)x0.z, (_Float16)x0.w,
               (_Float16)x1.x, (_Float16)x1.y, (_Float16)x1.z, (_Float16)x1.w};
}

// ============ Fused wea+scan: 512 blocks (8/batch) x 256 thr ============
// Phase 1: each block computes its batch's w/e/a (13 MFMA tiles over 4 waves,
//   8x redundant across the batch's 8 blocks) -> LDS (ea full, w 8-row slice).
// Phase 2: block-local __syncthreads, then the R5-verified RW=2 scan from LDS,
//   f16 partials -> pbase slice s.  No cross-block communication at all.
__global__ __launch_bounds__(256) void wea_scan(
    const int* __restrict__ skills, const int* __restrict__ responses,
    const float* __restrict__ k_emb, const float* __restrict__ v_emb,
    const float* __restrict__ Mk, const float* __restrict__ eW,
    const float* __restrict__ eb, const float* __restrict__ aW,
    const float* __restrict__ ab, const float* __restrict__ Mv0,
    unsigned short* __restrict__ pbase)
{
  __shared__ unsigned ea_lds[TT * 64];        // 51200 B: (e,a) f16 pairs
  __shared__ unsigned short w_lds[TT * 8];    // 3200 B:  w, this block's 8 m-rows
  __shared__ float red[2][SCH * 256];         // 20480 B: scan partial buffer
  // total 74880 B -> 2 blocks/CU; 512 blocks = 1 full round at 8 waves/CU

  const int tid  = threadIdx.x;
  const int wv   = tid >> 6, lane = tid & 63;
  const int b    = blockIdx.x >> 3, s = blockIdx.x & 7;
  const int lr   = lane & 15;                 // A-row / B-col / D-col
  const int lg   = lane >> 4;                 // k-group (8 f16 each)
  const int cw   = s >> 1, lrh = s & 1;       // w-slice selector: c==cw, lr>>3==lrh

  // ---- Phase 1: wea for batch b; tiles t = wv, wv+4, wv+8 [, wv+12] ----
  {
    float ebv[4], abv[4];
    #pragma unroll
    for (int c = 0; c < 4; ++c) { ebv[c] = eb[16 * c + lr]; abv[c] = ab[16 * c + lr]; }

    #pragma unroll 1
    for (int t = wv; t < 13; t += 4) {
      const int rbase = t * 16;
      const int rl    = min(rbase + lr, TT - 1);     // clamp (tile 12 is half)
      const int row   = b * TT + rl;
      const int sk = skills[row];
      int rr = responses[row]; rr = (rr > -1) ? rr : 0;   // masked_r
      const float4* kq = (const float4*)(k_emb + (size_t)sk * 64);
      const float4* vq = (const float4*)(v_emb + (size_t)(sk + NSK * rr) * 64);
      v8h ak[2], av[2];
      #pragma unroll
      for (int u = 0; u < 2; ++u) {
        const int o = u * 8 + lg * 2;
        ak[u] = pk8(kq[o], kq[o + 1]);
        av[u] = pk8(vq[o], vq[o + 1]);
      }

      v4f acK[4], acE[4], acA[4];
      #pragma unroll
      for (int c = 0; c < 4; ++c) {
        acK[c] = (v4f){0.f, 0.f, 0.f, 0.f};
        acE[c] = (v4f){0.f, 0.f, 0.f, 0.f};
        acA[c] = (v4f){0.f, 0.f, 0.f, 0.f};
      }
      #pragma unroll
      for (int c = 0; c < 4; ++c) {
        const float4* mq = (const float4*)(Mk + (size_t)(16 * c + lr) * 64);
        const float4* eq = (const float4*)(eW + (size_t)(16 * c + lr) * 64);
        const float4* aq = (const float4*)(aW + (size_t)(16 * c + lr) * 64);
        #pragma unroll
        for (int u = 0; u < 2; ++u) {
          const int o = u * 8 + lg * 2;
          const v8h bm = pk8(mq[o], mq[o + 1]);
          const v8h be = pk8(eq[o], eq[o + 1]);
          const v8h ba = pk8(aq[o], aq[o + 1]);
          acK[c] = __builtin_amdgcn_mfma_f32_16x16x32_f16(ak[u], bm, acK[c], 0, 0, 0);
          acE[c] = __builtin_amdgcn_mfma_f32_16x16x32_f16(av[u], be, acE[c], 0, 0, 0);
          acA[c] = __builtin_amdgcn_mfma_f32_16x16x32_f16(av[u], ba, acA[c], 0, 0, 0);
        }
      }

      float rs[4];
      #pragma unroll
      for (int q = 0; q < 4; ++q) {
        float m = fmaxf(fmaxf(acK[0][q], acK[1][q]), fmaxf(acK[2][q], acK[3][q]));
        #pragma unroll
        for (int off = 8; off; off >>= 1) m = fmaxf(m, __shfl_xor(m, off));
        float sm = 0.f;
        #pragma unroll
        for (int c = 0; c < 4; ++c) {
          acK[c][q] = __expf(acK[c][q] - m);
          sm += acK[c][q];
        }
        #pragma unroll
        for (int off = 8; off; off >>= 1) sm += __shfl_xor(sm, off);
        rs[q] = frcp(sm);
      }

      #pragma unroll
      for (int c = 0; c < 4; ++c) {
        const int j = 16 * c + lr;
        #pragma unroll
        for (int q = 0; q < 4; ++q) {
          const int rloc = rbase + lg * 4 + q;       // D row
          if (rloc < TT) {
            const float ev  = sigm(acE[c][q] + ebv[c]);
            const float avv = tanh_fast(acA[c][q] + abv[c]);
            ea_lds[rloc * 64 + j] = pack2h(ev, avv);
            if (c == cw && (lr >> 3) == lrh)         // j in [8s, 8s+8)
              w_lds[rloc * 8 + (lr & 7)] = f16bits(acK[c][q] * rs[q]);
          }
        }
      }
    }
  }
  __syncthreads();

  // ---- Phase 2: scan over this block's 8 m-rows (RW=2/wave, R5-verified) ----
  {
    const int m0 = s * 8 + wv * RW;
    unsigned short* ps = pbase + (size_t)s * PSTR;
    const size_t base = (size_t)b * TT;
    float Mv[RW];
    #pragma unroll
    for (int i = 0; i < RW; ++i) Mv[i] = Mv0[(size_t)(m0 + i) * 64 + lane];

    #pragma unroll 1
    for (int ch = 0; ch < TT / SCH; ++ch) {          // 20 chunks, 1 sync each
      const int t0 = ch * SCH;
      float* rbuf = red[ch & 1];
      unsigned eab[SCH], wvb[SCH];
      #pragma unroll
      for (int k = 0; k < SCH; ++k) {
        eab[k] = ea_lds[(t0 + k) * 64 + lane];
        wvb[k] = (unsigned)w_lds[(t0 + k) * 8 + wv * RW + (lane & (RW - 1))];
      }
      #pragma unroll
      for (int k = 0; k < SCH; ++k) {
        const float ev = f16lo(eab[k]), av = f16hi(eab[k]);
        float rp = 0.f;
        #pragma unroll
        for (int i = 0; i < RW; ++i) {
          const float wm = f16lo(ulane_bcast(wvb[k], i));  // w[m0+i] in lane i
          rp = fmaf(wm, Mv[i], rp);          // read uses PRE-update Mv
          float tp = fmaf(-ev, Mv[i], av);   // a - e*Mv
          Mv[i] = fmaf(wm, tp, Mv[i]);       // Mv += w*(a - e*Mv)
        }
        rbuf[k * 256 + wv * 64 + lane] = rp;
      }
      __syncthreads();
      for (int k = wv; k < SCH; k += 4) {            // 4 waves reduce 10 steps
        const float* rr2 = rbuf + k * 256;
        const float v = (rr2[lane] + rr2[64 + lane]) + (rr2[128 + lane] + rr2[192 + lane]);
        ps[(base + t0 + k) * 64 + lane] = f16bits(v);
      }
      // no trailing sync: next chunk writes red[(ch+1)&1]; the sync inside the
      // next iteration orders reduce(ch) before compute(ch+2) reuses red[ch&1].
    }
  }
}

// ============ Pass C (MFMA, R5-verified): 199 blocks x 256 thr, 16 outputs/wave ============
__global__ __launch_bounds__(256) void fp_mfma(
    const int* __restrict__ skills, const float* __restrict__ k_emb,
    const float* __restrict__ fW, const float* __restrict__ fb,
    const float* __restrict__ pW, const float* __restrict__ pb,
    const unsigned short* __restrict__ pbase,
    float* __restrict__ out)
{
  const int tid  = threadIdx.x;
  const int wv   = tid >> 6, lane = tid & 63;
  const int lr   = lane & 15;                        // A-row / B-col index
  const int lg   = lane >> 4;                        // k-group
  const int o0   = (blockIdx.x * 4 + wv) * 16;       // first output idx of this wave

  const unsigned idx = o0 + lr;
  const unsigned bb  = idx / 199u;
  const unsigned t2  = idx - bb * 199u;
  const int srow     = (int)(idx + bb + 1u);         // source row b*200 + t + 1

  v8h ar[4];
  #pragma unroll
  for (int t = 0; t < 2; ++t) {
    const size_t eo = (size_t)srow * 64 + t * 32 + lg * 8;   // ushort offset
    V8U s0, s1, s2, s3;
    s0.u = *(const uint4*)&pbase[eo];
    s1.u = *(const uint4*)&pbase[eo + PSTR];
    s2.u = *(const uint4*)&pbase[eo + 2 * PSTR];
    s3.u = *(const uint4*)&pbase[eo + 3 * PSTR];
    v8h acc = (s0.h + s1.h) + (s2.h + s3.h);
    s0.u = *(const uint4*)&pbase[eo + 4 * PSTR];
    s1.u = *(const uint4*)&pbase[eo + 5 * PSTR];
    s2.u = *(const uint4*)&pbase[eo + 6 * PSTR];
    s3.u = *(const uint4*)&pbase[eo + 7 * PSTR];
    ar[t] = acc + ((s0.h + s1.h) + (s2.h + s3.h));
  }
  {
    const float4* kq = (const float4*)(k_emb + (size_t)skills[srow] * 64);
    #pragma unroll
    for (int t = 2; t < 4; ++t) {
      const int o = (t - 2) * 8 + lg * 2;
      ar[t] = pk8(kq[o], kq[o + 1]);
    }
  }

  float fbv[4], pwv[4];
  #pragma unroll
  for (int c = 0; c < 4; ++c) { fbv[c] = fb[16 * c + lr]; pwv[c] = pW[16 * c + lr]; }

  v4f acc[4];
  #pragma unroll
  for (int c = 0; c < 4; ++c) acc[c] = (v4f){0.f, 0.f, 0.f, 0.f};

  const float4* fq = (const float4*)fW;
  #pragma unroll
  for (int c = 0; c < 4; ++c) {
    const int jb = (16 * c + lr) * 32;               // float4 row base
    #pragma unroll
    for (int t = 0; t < 4; ++t) {
      const int o = jb + t * 8 + lg * 2;
      const v8h bf = pk8(fq[o], fq[o + 1]);
      acc[c] = __builtin_amdgcn_mfma_f32_16x16x32_f16(ar[t], bf, acc[c], 0, 0, 0);
    }
  }

  const float pb0 = pb[0];
  #pragma unroll
  for (int q = 0; q < 4; ++q) {
    float s = 0.f;
    #pragma unroll
    for (int c = 0; c < 4; ++c)
      s += tanh_fast(acc[c][q] + fbv[c]) * pwv[c];
    #pragma unroll
    for (int off = 8; off; off >>= 1) s += __shfl_xor(s, off);
    if (lr == lg * 4 + q)                            // this lane owns row lg*4+q
      out[(size_t)bb * (TT - 1) + t2] = sigm(s + pb0);
  }
}

extern "C" void kernel_launch(void* const* d_in, const int* in_sizes, int n_in,
                              void* d_out, int out_size, void* d_ws, size_t ws_size,
                              hipStream_t stream) {
  const int* skills    = (const int*)d_in[0];
  const int* responses = (const int*)d_in[1];
  const float* k_emb   = (const float*)d_in[2];
  const float* v_emb   = (const float*)d_in[3];
  const float* Mk      = (const float*)d_in[4];
  const float* Mv0     = (const float*)d_in[5];
  const float* fW      = (const float*)d_in[6];
  const float* fb      = (const float*)d_in[7];
  const float* eW      = (const float*)d_in[8];
  const float* eb      = (const float*)d_in[9];
  const float* aW      = (const float*)d_in[10];
  const float* ab      = (const float*)d_in[11];
  const float* pW      = (const float*)d_in[12];
  const float* pb      = (const float*)d_in[13];
  (void)in_sizes; (void)n_in; (void)out_size; (void)ws_size;

  // workspace: 8 f16 partial arrays (1.6 MB each, 13.1 MB total)
  unsigned short* pbase = (unsigned short*)d_ws;

  wea_scan<<<dim3(BB * NSPLIT), 256, 0, stream>>>(
      skills, responses, k_emb, v_emb, Mk, eW, eb, aW, ab, Mv0, pbase);
  fp_mfma<<<dim3(199), 256, 0, stream>>>(
      skills, k_emb, fW, fb, pW, pb, pbase, (float*)d_out);
}

// Round 7
// 127.601 us; speedup vs baseline: 1.0361x; 1.0361x over previous
//
#include <hip/hip_runtime.h>
#include <stdint.h>

#define NSK 1000
#define TT  200
#define BB  64
#define NROW (BB * TT)      // 12800
#define NOUT (BB * (TT-1))  // 12736
#define CH  10              // scan chunk; red dbuf = 2*CH*256 floats = 20 KB -> 4 blocks/CU
#define RW  1               // scan Mv rows per wave (16-way M split: 16 blocks/batch)
#define NSPLIT 16
#define PSTR ((size_t)NROW * 64)   // partial-array stride (elements)

__device__ __forceinline__ float frcp(float x) { return __builtin_amdgcn_rcpf(x); }
__device__ __forceinline__ float sigm(float x) { return frcp(1.f + __expf(-x)); }
__device__ __forceinline__ float tanh_fast(float x) {
  return fmaf(-2.f, frcp(1.f + __expf(2.f * x)), 1.f);   // 1 - 2/(1+e^2x)
}

typedef _Float16 half2v __attribute__((ext_vector_type(2)));
typedef _Float16 v8h __attribute__((ext_vector_type(8)));   // MFMA A/B frag (4 VGPR)
typedef float    v4f __attribute__((ext_vector_type(4)));   // MFMA C/D frag
union H2U { unsigned u; half2v h; };
union V8U { uint4 u; v8h h; };
__device__ __forceinline__ unsigned pack2h(float a, float b) {
  H2U x; x.h = (half2v){(_Float16)a, (_Float16)b}; return x.u;
}
__device__ __forceinline__ unsigned short f16bits(float x) {
  H2U u; u.h = (half2v){(_Float16)x, (_Float16)0.f}; return (unsigned short)(u.u & 0xffffu);
}
__device__ __forceinline__ float f16lo(unsigned bits) {
  H2U u; u.u = bits; return (float)u.h.x;
}
__device__ __forceinline__ float f16hi(unsigned bits) {
  H2U u; u.u = bits; return (float)u.h.y;
}
__device__ __forceinline__ v8h pk8(float4 x0, float4 x1) {
  return (v8h){(_Float16)x0.x, (_Float16)x0.y, (_Float16)x0.z, (_Float16)x0.w,
               (_Float16)x1.x, (_Float16)x1.y, (_Float16)x1.z, (_Float16)x1.w};
}

// ============ Pass A (MFMA, R4-verified): 400 blocks x 128 thr, 16 rows/wave ============
// A: row=lane&15, k=(lane>>4)*8+e.  B: col=lane&15, same k.  D: col=lane&15, row=(lane>>4)*4+reg.
__global__ __launch_bounds__(128) void wea_mfma(
    const int* __restrict__ skills, const int* __restrict__ responses,
    const float* __restrict__ k_emb, const float* __restrict__ v_emb,
    const float* __restrict__ Mk, const float* __restrict__ eW,
    const float* __restrict__ eb, const float* __restrict__ aW,
    const float* __restrict__ ab,
    unsigned* __restrict__ ea_ws, unsigned short* __restrict__ w16_ws)
{
  const int tid  = threadIdx.x;
  const int wv   = tid >> 6, lane = tid & 63;
  const int tile = blockIdx.x * 2 + wv;              // 400*2 = 800 tiles
  const int r0   = tile * 16;
  const int lr   = lane & 15;                        // A-row / B-col / D-col
  const int lg   = lane >> 4;                        // k-group (8 f16 each)

  const int sk = skills[r0 + lr];
  int rr = responses[r0 + lr]; rr = (rr > -1) ? rr : 0;   // masked_r
  const int vrow = sk + NSK * rr;

  const float4* kq = (const float4*)(k_emb + (size_t)sk * 64);
  const float4* vq = (const float4*)(v_emb + (size_t)vrow * 64);
  v8h ak[2], av[2];
  #pragma unroll
  for (int t = 0; t < 2; ++t) {
    const int o = t * 8 + lg * 2;                    // float4 index within row
    ak[t] = pk8(kq[o], kq[o + 1]);
    av[t] = pk8(vq[o], vq[o + 1]);
  }

  float ebv[4], abv[4];
  #pragma unroll
  for (int c = 0; c < 4; ++c) { ebv[c] = eb[16 * c + lr]; abv[c] = ab[16 * c + lr]; }

  v4f acK[4], acE[4], acA[4];
  #pragma unroll
  for (int c = 0; c < 4; ++c) {
    acK[c] = (v4f){0.f, 0.f, 0.f, 0.f};
    acE[c] = (v4f){0.f, 0.f, 0.f, 0.f};
    acA[c] = (v4f){0.f, 0.f, 0.f, 0.f};
  }

  #pragma unroll
  for (int c = 0; c < 4; ++c) {
    const float4* mq = (const float4*)(Mk + (size_t)(16 * c + lr) * 64);
    const float4* eq = (const float4*)(eW + (size_t)(16 * c + lr) * 64);
    const float4* aq = (const float4*)(aW + (size_t)(16 * c + lr) * 64);
    #pragma unroll
    for (int t = 0; t < 2; ++t) {
      const int o = t * 8 + lg * 2;
      const v8h bm = pk8(mq[o], mq[o + 1]);
      const v8h be = pk8(eq[o], eq[o + 1]);
      const v8h ba = pk8(aq[o], aq[o + 1]);
      acK[c] = __builtin_amdgcn_mfma_f32_16x16x32_f16(ak[t], bm, acK[c], 0, 0, 0);
      acE[c] = __builtin_amdgcn_mfma_f32_16x16x32_f16(av[t], be, acE[c], 0, 0, 0);
      acA[c] = __builtin_amdgcn_mfma_f32_16x16x32_f16(av[t], ba, acA[c], 0, 0, 0);
    }
  }

  float rs[4];
  #pragma unroll
  for (int q = 0; q < 4; ++q) {
    float m = fmaxf(fmaxf(acK[0][q], acK[1][q]), fmaxf(acK[2][q], acK[3][q]));
    #pragma unroll
    for (int off = 8; off; off >>= 1) m = fmaxf(m, __shfl_xor(m, off));
    float s = 0.f;
    #pragma unroll
    for (int c = 0; c < 4; ++c) {
      acK[c][q] = __expf(acK[c][q] - m);
      s += acK[c][q];
    }
    #pragma unroll
    for (int off = 8; off; off >>= 1) s += __shfl_xor(s, off);
    rs[q] = frcp(s);
  }

  #pragma unroll
  for (int c = 0; c < 4; ++c) {
    const int j = 16 * c + lr;
    #pragma unroll
    for (int q = 0; q < 4; ++q) {
      const int row = r0 + lg * 4 + q;
      w16_ws[(size_t)row * 64 + j] = f16bits(acK[c][q] * rs[q]);
      const float ev = sigm(acE[c][q] + ebv[c]);
      const float avv = tanh_fast(acA[c][q] + abv[c]);
      ea_ws[(size_t)row * 64 + j] = pack2h(ev, avv);
    }
  }
}

// ============ Pass B: 1024 blocks x 256 thr, 16 blocks/batch (4 M-rows each) ============
// 20 KB LDS -> 4 blocks/CU, 16 waves/CU (4/SIMD).  RW=1: wave's w is a uniform load.
__global__ __launch_bounds__(256) void scan_kernel(
    const float* __restrict__ Mv0,
    const unsigned* __restrict__ ea_ws, const unsigned short* __restrict__ w16_ws,
    unsigned short* __restrict__ pbase)
{
  __shared__ float red[2][CH * 256];                 // 20 KB
  const int b    = blockIdx.x >> 4;
  const int s    = blockIdx.x & 15;
  const int wave = threadIdx.x >> 6;
  const int lane = threadIdx.x & 63;
  const size_t base = (size_t)b * TT;
  const int m0   = s * 4 + wave;                     // this wave's single m-row
  unsigned short* ps = pbase + (size_t)s * PSTR;

  float Mv = Mv0[(size_t)m0 * 64 + lane];

  const unsigned* eap = ea_ws + base * 64;
  const unsigned short* wp = w16_ws + base * 64;

  unsigned ea0[CH], wv0[CH], ea1[CH], wv1[CH];
  #pragma unroll
  for (int k = 0; k < CH; ++k) {
    ea0[k] = eap[k * 64 + lane];
    wv0[k] = (unsigned)wp[k * 64 + m0];
  }
  for (int ch = 0; ch < TT / CH; ch += 2) {          // 20 chunks
    // prefetch chunk ch+1
    #pragma unroll
    for (int k = 0; k < CH; ++k) {
      ea1[k] = eap[((ch + 1) * CH + k) * 64 + lane];
      wv1[k] = (unsigned)wp[((ch + 1) * CH + k) * 64 + m0];
    }
    #pragma unroll
    for (int k = 0; k < CH; ++k) {
      const float ev = f16lo(ea0[k]), av = f16hi(ea0[k]);
      const float wm = f16lo(wv0[k]);
      red[0][k * 256 + wave * 64 + lane] = wm * Mv;  // read uses PRE-update Mv
      Mv = fmaf(wm, fmaf(-ev, Mv, av), Mv);          // Mv += w*(a - e*Mv)
    }
    __syncthreads();
    for (int k = wave; k < CH; k += 4) {
      const float* rr = red[0] + k * 256;
      const float v = (rr[lane] + rr[64 + lane]) + (rr[128 + lane] + rr[192 + lane]);
      ps[(base + ch * CH + k) * 64 + lane] = f16bits(v);
    }
    // prefetch chunk ch+2
    if ((ch + 2) * CH < TT) {
      #pragma unroll
      for (int k = 0; k < CH; ++k) {
        ea0[k] = eap[((ch + 2) * CH + k) * 64 + lane];
        wv0[k] = (unsigned)wp[((ch + 2) * CH + k) * 64 + m0];
      }
    }
    #pragma unroll
    for (int k = 0; k < CH; ++k) {
      const float ev = f16lo(ea1[k]), av = f16hi(ea1[k]);
      const float wm = f16lo(wv1[k]);
      red[1][k * 256 + wave * 64 + lane] = wm * Mv;
      Mv = fmaf(wm, fmaf(-ev, Mv, av), Mv);
    }
    __syncthreads();
    for (int k = wave; k < CH; k += 4) {
      const float* rr = red[1] + k * 256;
      const float v = (rr[lane] + rr[64 + lane]) + (rr[128 + lane] + rr[192 + lane]);
      ps[(base + (ch + 1) * CH + k) * 64 + lane] = f16bits(v);
    }
  }
}

// ============ Pass C (MFMA, R5-verified + 16 partials): 199 blocks x 256 thr ============
__global__ __launch_bounds__(256) void fp_mfma(
    const int* __restrict__ skills, const float* __restrict__ k_emb,
    const float* __restrict__ fW, const float* __restrict__ fb,
    const float* __restrict__ pW, const float* __restrict__ pb,
    const unsigned short* __restrict__ pbase,
    float* __restrict__ out)
{
  const int tid  = threadIdx.x;
  const int wv   = tid >> 6, lane = tid & 63;
  const int lr   = lane & 15;                        // A-row / B-col index
  const int lg   = lane >> 4;                        // k-group
  const int o0   = (blockIdx.x * 4 + wv) * 16;       // first output idx of this wave

  const unsigned idx = o0 + lr;
  const unsigned bb  = idx / 199u;
  const unsigned t2  = idx - bb * 199u;
  const int srow     = (int)(idx + bb + 1u);         // source row b*200 + t + 1

  // A fragments: t=0,1 -> reads (pairwise tree over 16 f16 partials); t=2,3 -> k_emb.
  v8h ar[4];
  #pragma unroll
  for (int t = 0; t < 2; ++t) {
    const size_t eo = (size_t)srow * 64 + t * 32 + lg * 8;   // ushort offset
    v8h g[4];
    #pragma unroll
    for (int pp = 0; pp < 4; ++pp) {
      V8U s0, s1, s2, s3;
      s0.u = *(const uint4*)&pbase[eo + (size_t)(4 * pp) * PSTR];
      s1.u = *(const uint4*)&pbase[eo + (size_t)(4 * pp + 1) * PSTR];
      s2.u = *(const uint4*)&pbase[eo + (size_t)(4 * pp + 2) * PSTR];
      s3.u = *(const uint4*)&pbase[eo + (size_t)(4 * pp + 3) * PSTR];
      g[pp] = (s0.h + s1.h) + (s2.h + s3.h);
    }
    ar[t] = (g[0] + g[1]) + (g[2] + g[3]);
  }
  {
    const float4* kq = (const float4*)(k_emb + (size_t)skills[srow] * 64);
    #pragma unroll
    for (int t = 2; t < 4; ++t) {
      const int o = (t - 2) * 8 + lg * 2;
      ar[t] = pk8(kq[o], kq[o + 1]);
    }
  }

  float fbv[4], pwv[4];
  #pragma unroll
  for (int c = 0; c < 4; ++c) { fbv[c] = fb[16 * c + lr]; pwv[c] = pW[16 * c + lr]; }

  v4f acc[4];
  #pragma unroll
  for (int c = 0; c < 4; ++c) acc[c] = (v4f){0.f, 0.f, 0.f, 0.f};

  const float4* fq = (const float4*)fW;
  #pragma unroll
  for (int c = 0; c < 4; ++c) {
    const int jb = (16 * c + lr) * 32;               // float4 row base
    #pragma unroll
    for (int t = 0; t < 4; ++t) {
      const int o = jb + t * 8 + lg * 2;
      const v8h bf = pk8(fq[o], fq[o + 1]);
      acc[c] = __builtin_amdgcn_mfma_f32_16x16x32_f16(ar[t], bf, acc[c], 0, 0, 0);
    }
  }

  const float pb0 = pb[0];
  #pragma unroll
  for (int q = 0; q < 4; ++q) {
    float s = 0.f;
    #pragma unroll
    for (int c = 0; c < 4; ++c)
      s += tanh_fast(acc[c][q] + fbv[c]) * pwv[c];
    #pragma unroll
    for (int off = 8; off; off >>= 1) s += __shfl_xor(s, off);
    if (lr == lg * 4 + q)                            // this lane owns row lg*4+q
      out[(size_t)bb * (TT - 1) + t2] = sigm(s + pb0);
  }
}

extern "C" void kernel_launch(void* const* d_in, const int* in_sizes, int n_in,
                              void* d_out, int out_size, void* d_ws, size_t ws_size,
                              hipStream_t stream) {
  const int* skills    = (const int*)d_in[0];
  const int* responses = (const int*)d_in[1];
  const float* k_emb   = (const float*)d_in[2];
  const float* v_emb   = (const float*)d_in[3];
  const float* Mk      = (const float*)d_in[4];
  const float* Mv0     = (const float*)d_in[5];
  const float* fW      = (const float*)d_in[6];
  const float* fb      = (const float*)d_in[7];
  const float* eW      = (const float*)d_in[8];
  const float* eb      = (const float*)d_in[9];
  const float* aW      = (const float*)d_in[10];
  const float* ab      = (const float*)d_in[11];
  const float* pW      = (const float*)d_in[12];
  const float* pb      = (const float*)d_in[13];
  (void)in_sizes; (void)n_in; (void)out_size; (void)ws_size;

  // f16-packed scratch: ea (3.3MB) | w16 (1.6MB) | 16 partial arrays (1.6MB each)
  unsigned* ea_ws        = (unsigned*)d_ws;
  unsigned short* w16_ws = (unsigned short*)(ea_ws + (size_t)NROW * 64);
  unsigned short* pbase  = w16_ws + PSTR;

  wea_mfma<<<dim3(400), 128, 0, stream>>>(
      skills, responses, k_emb, v_emb, Mk, eW, eb, aW, ab, ea_ws, w16_ws);
  scan_kernel<<<dim3(BB * NSPLIT), 256, 0, stream>>>(Mv0, ea_ws, w16_ws, pbase);
  fp_mfma<<<dim3(199), 256, 0, stream>>>(
      skills, k_emb, fW, fb, pW, pb, pbase, (float*)d_out);
}